// Round 2
// baseline (2889.888 us; speedup 1.0000x reference)
//
#include <hip/hip_runtime.h>
#include <hip/hip_bf16.h>
#include <cstdint>
#include <cstddef>

// Problem constants
#define T_TOK 4096
#define HID   4096
#define INT_  14336
#define RNK   318
#define RP    384     // rank padded
#define TSPLIT 8      // split-K factor for t2
#define TSLICE 1792   // 14336 / 8

typedef __hip_bfloat16 bf16;
typedef __attribute__((ext_vector_type(8)))  __bf16 bf16x8;
typedef __attribute__((ext_vector_type(16))) float  f32x16;

// ---------------------------------------------------------------------------
__device__ __forceinline__ void gload16(const bf16* g, void* l) {
  __builtin_amdgcn_global_load_lds(
      (__attribute__((address_space(1))) void*)(uintptr_t)(const void*)g,
      (__attribute__((address_space(3))) void*)l,
      16, 0, 0);
}

// ---------------------------------------------------------------------------
__global__ void k_convert(const float* __restrict__ s, bf16* __restrict__ d, long n) {
  long i = ((long)blockIdx.x * blockDim.x + threadIdx.x) * 4;
  long stride = (long)gridDim.x * blockDim.x * 4;
  for (; i < n; i += stride) {
    float4 v = *(const float4*)(s + i);
    __hip_bfloat162 p0 = __float22bfloat162_rn(make_float2(v.x, v.y));
    __hip_bfloat162 p1 = __float22bfloat162_rn(make_float2(v.z, v.w));
    *(__hip_bfloat162*)(d + i)     = p0;
    *(__hip_bfloat162*)(d + i + 2) = p1;
  }
}

__global__ void k_convert_pad(const float* __restrict__ s, bf16* __restrict__ d,
                              int srows, int scols, int dcols, long total) {
  long i = (long)blockIdx.x * blockDim.x + threadIdx.x;
  long stride = (long)gridDim.x * blockDim.x;
  for (; i < total; i += stride) {
    int r = (int)(i / dcols), c = (int)(i % dcols);
    float v = (r < srows && c < scols) ? s[(long)r * scols + c] : 0.f;
    d[i] = __float2bfloat16(v);
  }
}

// sum 8 fp32 partial slices -> bf16
__global__ void k_reduce8(const float* __restrict__ part, bf16* __restrict__ out,
                          long n, long slice) {
  long i = ((long)blockIdx.x * blockDim.x + threadIdx.x) * 4;
  if (i >= n) return;
  float4 s = *(const float4*)(part + i);
#pragma unroll
  for (int z = 1; z < TSPLIT; z++) {
    float4 v = *(const float4*)(part + (long)z * slice + i);
    s.x += v.x; s.y += v.y; s.z += v.z; s.w += v.w;
  }
  __hip_bfloat162 p0 = __float22bfloat162_rn(make_float2(s.x, s.y));
  __hip_bfloat162 p1 = __float22bfloat162_rn(make_float2(s.z, s.w));
  *(__hip_bfloat162*)(out + i)     = p0;
  *(__hip_bfloat162*)(out + i + 2) = p1;
}

// ---------------------------------------------------------------------------
// C[M,N] = A[M,K] @ B[N,K]^T, two K-segments, 128x128 tile, BK=64,
// 4 waves x (2x2 of 32x32x16 bf16 MFMA) = 64x64 per wave.
// global_load_lds staging, XOR-swizzled LDS (swizzle on source address).
// EPI: 0 = bf16 store, 1 = silu(acc)*Up -> bf16, 2 = fp32 store,
//      3 = fp32 partial store at slice blockIdx.z (split-K)
template <int EPI>
__global__ __launch_bounds__(256)
void k_gemm(const bf16* __restrict__ A0, int lda0,
            const bf16* __restrict__ B0, int ldb0, int K0,
            const bf16* __restrict__ A1, int lda1,
            const bf16* __restrict__ B1, int ldb1, int K1,
            int N, void* __restrict__ Cout, const bf16* __restrict__ Up,
            int kslice) {
  __shared__ __align__(128) bf16 As[128 * 64];
  __shared__ __align__(128) bf16 Bs[128 * 64];

  if (kslice) {                       // split-K: shift K window per z-slice
    size_t ko = (size_t)blockIdx.z * kslice;
    A0 += ko; B0 += ko;
  }

  const int tid   = threadIdx.x;
  const int wv    = tid >> 6;
  const int lane  = tid & 63;
  const int l31   = lane & 31;
  const int khalf = lane >> 5;        // 0/1 : which K-half of the fragment
  const int row0  = blockIdx.y * 128;
  const int col0  = blockIdx.x * 128;
  const int wrow  = (wv >> 1) * 64;
  const int wcol  = (wv & 1) * 64;

  // staging mapping: 8 rows/wave-load, physical chunk (lane&7) at row srow
  // holds logical chunk (lane&7)^srow  ->  logical q lives at q^(row&7)
  const int srow = lane >> 3;
  const int sq   = (lane & 7) ^ srow;

  // fragment LDS byte offsets for k-step 0; step s applies ^ (s<<5)
  int a_off[2], b_off[2];
#pragma unroll
  for (int i = 0; i < 2; i++) {
    int r = wrow + i * 32 + l31;
    a_off[i] = r * 128 + ((khalf ^ (r & 7)) << 4);
    int c = wcol + i * 32 + l31;
    b_off[i] = c * 128 + ((khalf ^ (c & 7)) << 4);
  }

  f32x16 acc[2][2] = {};

  const bf16* Aseg = A0; int ldaA = lda0;
  const bf16* Bseg = B0; int ldbB = ldb0;
  int Ks = K0;
#pragma unroll 1
  for (int seg = 0; seg < 2; seg++) {
    if (seg) {
      if (K1 == 0) break;
      Aseg = A1; ldaA = lda1; Bseg = B1; ldbB = ldb1; Ks = K1;
    }
    const int nkb = Ks >> 6;
#pragma unroll 1
    for (int kb = 0; kb < nkb; kb++) {
      __syncthreads();
#pragma unroll
      for (int i = 0; i < 4; i++) {
        const int wl = (wv << 2) + i;
        const int r  = (wl << 3) + srow;
        gload16(Aseg + (size_t)(row0 + r) * ldaA + (kb << 6) + (sq << 3),
                (char*)As + wl * 1024);
        gload16(Bseg + (size_t)(col0 + r) * ldbB + (kb << 6) + (sq << 3),
                (char*)Bs + wl * 1024);
      }
      __syncthreads();
#pragma unroll
      for (int s = 0; s < 4; s++) {
        bf16x8 af[2], bfr[2];
#pragma unroll
        for (int i = 0; i < 2; i++)
          af[i] = *(const bf16x8*)((const char*)As + (a_off[i] ^ (s << 5)));
#pragma unroll
        for (int j = 0; j < 2; j++)
          bfr[j] = *(const bf16x8*)((const char*)Bs + (b_off[j] ^ (s << 5)));
#pragma unroll
        for (int i = 0; i < 2; i++)
#pragma unroll
          for (int j = 0; j < 2; j++)
            acc[i][j] = __builtin_amdgcn_mfma_f32_32x32x16_bf16(
                af[i], bfr[j], acc[i][j], 0, 0, 0);
      }
    }
  }

  // C/D layout (32x32): col = lane&31, row = (reg&3) + 8*(reg>>2) + 4*khalf
  float* Cp = (float*)Cout;
  if (EPI == 3) Cp += (size_t)blockIdx.z * T_TOK * RP;
#pragma unroll
  for (int i = 0; i < 2; i++) {
#pragma unroll
    for (int j = 0; j < 2; j++) {
      const int cc = col0 + wcol + j * 32 + l31;
#pragma unroll
      for (int reg = 0; reg < 16; reg++) {
        const int rr = row0 + wrow + i * 32 + (reg & 3) + 8 * (reg >> 2) + 4 * khalf;
        const size_t idx = (size_t)rr * N + cc;
        float v = acc[i][j][reg];
        if (EPI == 0) {
          ((bf16*)Cout)[idx] = __float2bfloat16(v);
        } else if (EPI == 1) {
          float u  = __bfloat162float(Up[idx]);
          float sg = v / (1.f + __expf(-v));
          ((bf16*)Cout)[idx] = __float2bfloat16(sg * u);
        } else {
          Cp[idx] = v;
        }
      }
    }
  }
}

// ---------------------------------------------------------------------------
extern "C" void kernel_launch(void* const* d_in, const int* in_sizes, int n_in,
                              void* d_out, int out_size, void* d_ws, size_t ws_size,
                              hipStream_t stream) {
  const float* x   = (const float*)d_in[0];
  const float* W1  = (const float*)d_in[1];
  const float* W2  = (const float*)d_in[2];
  const float* W3  = (const float*)d_in[3];
  const float* du1 = (const float*)d_in[4];
  const float* dv1 = (const float*)d_in[5];
  const float* du2 = (const float*)d_in[6];
  const float* dv2 = (const float*)d_in[7];
  const float* du3 = (const float*)d_in[8];
  const float* dv3 = (const float*)d_in[9];

  bf16* p = (bf16*)d_ws;
  bf16* xb    = p; p += (size_t)T_TOK * HID;
  bf16* W1b   = p; p += (size_t)INT_ * HID;
  bf16* W2b   = p; p += (size_t)HID * INT_;
  bf16* W3b   = p; p += (size_t)INT_ * HID;
  bf16* du1b  = p; p += (size_t)INT_ * RP;
  bf16* du2b  = p; p += (size_t)HID * RP;
  bf16* du3b  = p; p += (size_t)INT_ * RP;
  bf16* dv13b = p; p += (size_t)(2 * RP) * HID;   // rows 0..383=dv1, 384..767=dv3
  bf16* dv2b  = p; p += (size_t)RP * INT_;
  bf16* t13b  = p; p += (size_t)T_TOK * (2 * RP); // cols 0..383=t1, 384..767=t3
  bf16* t2b   = p; p += (size_t)T_TOK * RP;
  bf16* upb   = p; p += (size_t)T_TOK * INT_;
  bf16* zb    = p; p += (size_t)T_TOK * INT_;
  // t2 fp32 partials alias upb (dead after the gate kernel reads it)
  float* t2part = (float*)upb;  // TSPLIT * T_TOK * RP * 4B = 50 MB < 117 MB

  // --- fp32 -> bf16 conversions ---
  k_convert<<<8192, 256, 0, stream>>>(x,  xb,  (long)T_TOK * HID);
  k_convert<<<8192, 256, 0, stream>>>(W1, W1b, (long)INT_ * HID);
  k_convert<<<8192, 256, 0, stream>>>(W2, W2b, (long)HID * INT_);
  k_convert<<<8192, 256, 0, stream>>>(W3, W3b, (long)INT_ * HID);
  k_convert_pad<<<4096, 256, 0, stream>>>(du1, du1b, INT_, RNK, RP, (long)INT_ * RP);
  k_convert_pad<<<4096, 256, 0, stream>>>(du2, du2b, HID, RNK, RP,  (long)HID * RP);
  k_convert_pad<<<4096, 256, 0, stream>>>(du3, du3b, INT_, RNK, RP, (long)INT_ * RP);
  k_convert_pad<<<4096, 256, 0, stream>>>(dv1, dv13b,             RNK, HID, HID, (long)RP * HID);
  k_convert_pad<<<4096, 256, 0, stream>>>(dv3, dv13b + (size_t)RP * HID, RNK, HID, HID, (long)RP * HID);
  k_convert_pad<<<4096, 256, 0, stream>>>(dv2, dv2b, RNK, INT_, INT_, (long)RP * INT_);

  // --- t13 = x @ [dv1;dv3]^T : [T, 768] ---
  k_gemm<0><<<dim3(2 * RP / 128, T_TOK / 128), 256, 0, stream>>>(
      xb, HID, dv13b, HID, HID, nullptr, 0, nullptr, 0, 0,
      2 * RP, t13b, nullptr, 0);

  // --- up = x@W3^T + t3@du3^T ---
  k_gemm<0><<<dim3(INT_ / 128, T_TOK / 128), 256, 0, stream>>>(
      xb, HID, W3b, HID, HID, t13b + RP, 2 * RP, du3b, RP, RP,
      INT_, upb, nullptr, 0);

  // --- z = silu(x@W1^T + t1@du1^T) * up ---
  k_gemm<1><<<dim3(INT_ / 128, T_TOK / 128), 256, 0, stream>>>(
      xb, HID, W1b, HID, HID, t13b, 2 * RP, du1b, RP, RP,
      INT_, zb, upb, 0);

  // --- t2 partials = z @ dv2^T, split-K over 8 slices ---
  k_gemm<3><<<dim3(RP / 128, T_TOK / 128, TSPLIT), 256, 0, stream>>>(
      zb, INT_, dv2b, INT_, TSLICE, nullptr, 0, nullptr, 0, 0,
      RP, t2part, nullptr, TSLICE);
  k_reduce8<<<(T_TOK * RP) / 4 / 256, 256, 0, stream>>>(
      t2part, t2b, (long)T_TOK * RP, (long)T_TOK * RP);

  // --- out = z@W2^T + t2@du2^T  (fp32) ---
  k_gemm<2><<<dim3(HID / 128, T_TOK / 128), 256, 0, stream>>>(
      zb, INT_, W2b, INT_, INT_, t2b, RP, du2b, RP, RP,
      HID, d_out, nullptr, 0);
}